// Round 11
// baseline (1030.725 us; speedup 1.0000x reference)
//
#include <hip/hip_runtime.h>

// Weighted 2-layer GCN, N=20000 nodes, E=320000 edges, T=4, F_IN=128, HID=256, F_OUT=128.
//
//  - BN subtracts batch mean right after h = agg@W + b -> biases cancel, never read.
//  - Aggregation commutes with GEMM. L1: gather-first. L2: GEMM-first, gather after.
//  - GEMMs on MFMA via split-bf16: D = Ah*Wh + Ah*Wl + Al*Wh (f32 accum).
//  - LDS tiles: 64B rows, 4x16B blocks, XOR swizzle blk ^= (row&3); staging via
//    global_load_lds with pre-swizzled per-lane SOURCE (linear dest).
//  - agg: 4 edge-streams/thread (16 edges in flight per block) with clamped
//    addresses + zero-weight tails -> no divergence, 8 outstanding gathers/thread.
//  - BN stats fused into producers (gemm1 epilogue for layer 1, agg2 epilogue
//    for layer 2) -> no separate stats passes.

#define T_DIM 4
#define F_DIM 128
#define HID   256
#define TF    512

typedef __attribute__((ext_vector_type(8))) short bf16x8;
typedef __attribute__((ext_vector_type(4))) float f32x4;

__device__ __forceinline__ ushort f2bf(float x) {
    union { float f; unsigned u; } v; v.f = x;
    unsigned r = v.u + 0x7FFF + ((v.u >> 16) & 1);
    return (ushort)(r >> 16);
}
__device__ __forceinline__ float bf2f(ushort b) {
    union { float f; unsigned u; } v; v.u = ((unsigned)b) << 16;
    return v.f;
}
__device__ __forceinline__ void gl_lds16(const void* gsrc, void* ldst) {
    __builtin_amdgcn_global_load_lds(
        (const __attribute__((address_space(1))) unsigned*)gsrc,
        (__attribute__((address_space(3))) unsigned*)ldst, 16, 0, 0);
}

// ---------------- CSR build ----------------
__global__ void count_kernel(const int* __restrict__ dst, int E, int* __restrict__ deg) {
    int e = blockIdx.x * blockDim.x + threadIdx.x;
    if (e < E) atomicAdd(&deg[dst[e]], 1);
}

__global__ void scan_kernel(const int* __restrict__ deg, int* __restrict__ row_start,
                            int* __restrict__ cursor, int n) {
    __shared__ int part[1024];
    int tid = threadIdx.x;
    int chunk = (n + 1023) >> 10;
    int begin = tid * chunk; if (begin > n) begin = n;
    int end = begin + chunk; if (end > n) end = n;
    int s = 0;
    for (int i = begin; i < end; ++i) s += deg[i];
    part[tid] = s;
    __syncthreads();
    for (int off = 1; off < 1024; off <<= 1) {
        int v = (tid >= off) ? part[tid - off] : 0;
        __syncthreads();
        part[tid] += v;
        __syncthreads();
    }
    int excl = (tid == 0) ? 0 : part[tid - 1];
    for (int i = begin; i < end; ++i) {
        row_start[i] = excl; cursor[i] = excl; excl += deg[i];
    }
    if (tid == 1023) row_start[n] = part[1023];
}

__global__ void fill_kernel(const int* __restrict__ src, const int* __restrict__ dst,
                            const float4* __restrict__ ew, int E,
                            int* __restrict__ cursor, int* __restrict__ esrc,
                            float4* __restrict__ ewr) {
    int e = blockIdx.x * blockDim.x + threadIdx.x;
    if (e < E) {
        int d = dst[e];
        int p = atomicAdd(&cursor[d], 1);
        esrc[p] = src[e];
        ewr[p] = ew[e];
    }
}

// ---------------- W transpose + bf16 split: W[K][NC] -> Wt_hi/lo[NC][K] ----------------
__global__ void wsplit_kernel(const float* __restrict__ W, int K, int NC,
                              ushort* __restrict__ hi, ushort* __restrict__ lo) {
    int idx = blockIdx.x * 256 + threadIdx.x;
    if (idx >= K * NC) return;
    int k = idx / NC, c = idx % NC;
    float x = W[idx];
    ushort h = f2bf(x);
    hi[(size_t)c * K + k] = h;
    lo[(size_t)c * K + k] = f2bf(x - bf2f(h));
}

// ---------------- aggregation: out[n,t,f] = sum_e ew[e,t]*x[src[e],t,f] ----------------
// 4 waves x 4 streams = 16 edges in flight. Clamped tail addresses, zero weights.
template<bool BF16OUT, bool DOSTATS>
__global__ __launch_bounds__(256) void agg_kernel(
        const float4* __restrict__ x4, const float* __restrict__ ewr,
        const int* __restrict__ row_start, const int* __restrict__ esrc,
        float4* __restrict__ out4, ushort* __restrict__ ohi, ushort* __restrict__ olo,
        float* __restrict__ sums, float* __restrict__ sqs) {
    const int n = blockIdx.x;
    const int tid = threadIdx.x;
    const int p = tid >> 6;          // wave = edge sub-slot
    const int q = tid & 63;          // float4 slot pair {2q, 2q+1}
    const int t = q >> 4;
    const int beg = row_start[n], end = row_start[n + 1];

    float4 aA[4], aB[4];
    #pragma unroll
    for (int st = 0; st < 4; ++st) {
        aA[st] = make_float4(0.f, 0.f, 0.f, 0.f);
        aB[st] = make_float4(0.f, 0.f, 0.f, 0.f);
    }
    const int last = end - 1;
    for (int i = beg; i < end; i += 16) {
        int sIdx[4]; float wv[4];
        #pragma unroll
        for (int st = 0; st < 4; ++st) {
            int e = i + 4 * st + p;
            int ec = (e < end) ? e : last;
            sIdx[st] = esrc[ec];
            wv[st] = (e < end) ? ewr[ec * 4 + t] : 0.f;
        }
        float4 va[4], vb[4];
        #pragma unroll
        for (int st = 0; st < 4; ++st) {
            const float4* xr = x4 + (size_t)sIdx[st] * 128 + 2 * q;
            va[st] = xr[0];
            vb[st] = xr[1];
        }
        #pragma unroll
        for (int st = 0; st < 4; ++st) {
            const float w = wv[st];
            aA[st].x = fmaf(w, va[st].x, aA[st].x); aA[st].y = fmaf(w, va[st].y, aA[st].y);
            aA[st].z = fmaf(w, va[st].z, aA[st].z); aA[st].w = fmaf(w, va[st].w, aA[st].w);
            aB[st].x = fmaf(w, vb[st].x, aB[st].x); aB[st].y = fmaf(w, vb[st].y, aB[st].y);
            aB[st].z = fmaf(w, vb[st].z, aB[st].z); aB[st].w = fmaf(w, vb[st].w, aB[st].w);
        }
    }
    float4 accA = make_float4(aA[0].x + aA[1].x + aA[2].x + aA[3].x,
                              aA[0].y + aA[1].y + aA[2].y + aA[3].y,
                              aA[0].z + aA[1].z + aA[2].z + aA[3].z,
                              aA[0].w + aA[1].w + aA[2].w + aA[3].w);
    float4 accB = make_float4(aB[0].x + aB[1].x + aB[2].x + aB[3].x,
                              aB[0].y + aB[1].y + aB[2].y + aB[3].y,
                              aB[0].z + aB[1].z + aB[2].z + aB[3].z,
                              aB[0].w + aB[1].w + aB[2].w + aB[3].w);

    __shared__ float4 red[3][128];
    __shared__ float chS[128], chQ[128];
    if (DOSTATS && tid < 128) { chS[tid] = 0.f; chQ[tid] = 0.f; }
    if (p) { red[p - 1][2 * q] = accA; red[p - 1][2 * q + 1] = accB; }
    __syncthreads();
    if (p == 0) {
        #pragma unroll
        for (int r = 0; r < 3; ++r) {
            float4 a = red[r][2 * q], b = red[r][2 * q + 1];
            accA.x += a.x; accA.y += a.y; accA.z += a.z; accA.w += a.w;
            accB.x += b.x; accB.y += b.y; accB.z += b.z; accB.w += b.w;
        }
        if (BF16OUT) {
            float v[8] = {accA.x, accA.y, accA.z, accA.w, accB.x, accB.y, accB.z, accB.w};
            uint4 hw, lw;
            unsigned hu[4], lu[4];
            #pragma unroll
            for (int j = 0; j < 4; ++j) {
                ushort h0 = f2bf(v[2 * j]), h1 = f2bf(v[2 * j + 1]);
                ushort l0 = f2bf(v[2 * j] - bf2f(h0)), l1 = f2bf(v[2 * j + 1] - bf2f(h1));
                hu[j] = (unsigned)h0 | ((unsigned)h1 << 16);
                lu[j] = (unsigned)l0 | ((unsigned)l1 << 16);
            }
            hw.x = hu[0]; hw.y = hu[1]; hw.z = hu[2]; hw.w = hu[3];
            lw.x = lu[0]; lw.y = lu[1]; lw.z = lu[2]; lw.w = lu[3];
            *(uint4*)&ohi[(size_t)n * TF + q * 8] = hw;
            *(uint4*)&olo[(size_t)n * TF + q * 8] = lw;
        } else {
            out4[(size_t)n * 128 + 2 * q] = accA;
            out4[(size_t)n * 128 + 2 * q + 1] = accB;
        }
        if (DOSTATS) {
            float v[8] = {accA.x, accA.y, accA.z, accA.w, accB.x, accB.y, accB.z, accB.w};
            #pragma unroll
            for (int u = 0; u < 8; ++u) {
                int ch = (q * 8 + u) & 127;
                atomicAdd(&chS[ch], v[u]);
                atomicAdd(&chQ[ch], v[u] * v[u]);
            }
        }
    }
    if (DOSTATS) {
        __syncthreads();
        if (tid < 128) {
            atomicAdd(&sums[tid], chS[tid]);
            atomicAdd(&sqs[tid], chQ[tid]);
        }
    }
}

// ---------------- MFMA GEMM (split bf16), out[r][c] f32, optional fused stats ----------------
// BM x 128 tile, BK=32, 4 waves. LDS rows = 64B (32 bf16), blk ^= (row&3) swizzle.
template<int BM, int K, int NC, bool FUSE, bool DOSTATS>
__global__ __launch_bounds__(256, 4) void gemm_mfma(
        const ushort* __restrict__ A_hi, const ushort* __restrict__ A_lo,
        const float* __restrict__ Af32,
        const ushort* __restrict__ Wt_hi, const ushort* __restrict__ Wt_lo,
        const float* __restrict__ scale, const float* __restrict__ shift,
        float* __restrict__ out, float* __restrict__ sums, float* __restrict__ sqs) {
    constexpr int BN = 128;
    constexpr int MT = BM / 64;               // m-tiles per wave (2 or 1)
    __shared__ __align__(16) unsigned char AsH[BM * 64], AsL[BM * 64];
    __shared__ __align__(16) unsigned char WsH[BN * 64], WsL[BN * 64];
    __shared__ float chS[128], chQ[128];
    const int tid = threadIdx.x;
    const int w = tid >> 6, l = tid & 63;
    const long rowbase = (long)blockIdx.y * BM;
    const int colbase = blockIdx.x * BN;

    if (DOSTATS && tid < 128) { chS[tid] = 0.f; chQ[tid] = 0.f; }

    f32x4 acc[MT][8];
    #pragma unroll
    for (int mt = 0; mt < MT; ++mt)
        #pragma unroll
        for (int nt = 0; nt < 8; ++nt) acc[mt][nt] = (f32x4){0.f, 0.f, 0.f, 0.f};

    for (int kb = 0; kb < K / 32; ++kb) {
        if (kb) __syncthreads();
        // ---- stage W tile (BN x 32) hi+lo via global_load_lds, pre-swizzled source
        {
            const int b = l & 3;
            #pragma unroll
            for (int cc = 0; cc < 2; ++cc) {
                int c = 2 * w + cc;
                int cl = c * 16 + (l >> 2);
                size_t go = (size_t)(colbase + cl) * K + kb * 32 + ((b ^ (cl & 3)) << 3);
                gl_lds16(Wt_hi + go, WsH + c * 1024);
                gl_lds16(Wt_lo + go, WsL + c * 1024);
            }
        }
        // ---- stage A tile
        if (!FUSE) {
            const int b = l & 3;
            #pragma unroll
            for (int cc = 0; cc < BM / 64; ++cc) {
                int c = w * (BM / 64) + cc;
                int r = c * 16 + (l >> 2);
                size_t go = (size_t)(rowbase + r) * K + kb * 32 + ((b ^ (r & 3)) << 3);
                gl_lds16(A_hi + go, AsH + c * 1024);
                gl_lds16(A_lo + go, AsL + c * 1024);
            }
        } else {
            #pragma unroll
            for (int pp = 0; pp < BM * 32 / 1024; ++pp) {
                int idx = pp * 256 + tid;
                int r = idx >> 3, k4 = idx & 7;
                float4 v = *(const float4*)&Af32[(rowbase + r) * K + kb * 32 + k4 * 4];
                int ch = kb * 32 + k4 * 4;
                float4 sc = *(const float4*)&scale[ch];
                float4 sh = *(const float4*)&shift[ch];
                v.x = fmaxf(fmaf(sc.x, v.x, sh.x), 0.f);
                v.y = fmaxf(fmaf(sc.y, v.y, sh.y), 0.f);
                v.z = fmaxf(fmaf(sc.z, v.z, sh.z), 0.f);
                v.w = fmaxf(fmaf(sc.w, v.w, sh.w), 0.f);
                ushort h[4], lo[4];
                float vv[4] = {v.x, v.y, v.z, v.w};
                #pragma unroll
                for (int j = 0; j < 4; ++j) {
                    h[j] = f2bf(vv[j]);
                    lo[j] = f2bf(vv[j] - bf2f(h[j]));
                }
                unsigned long long hq = (unsigned long long)((unsigned)h[0] | ((unsigned)h[1] << 16))
                                      | ((unsigned long long)((unsigned)h[2] | ((unsigned)h[3] << 16)) << 32);
                unsigned long long lq = (unsigned long long)((unsigned)lo[0] | ((unsigned)lo[1] << 16))
                                      | ((unsigned long long)((unsigned)lo[2] | ((unsigned)lo[3] << 16)) << 32);
                int off = r * 64 + (((k4 >> 1) ^ (r & 3)) << 4) + (k4 & 1) * 8;
                *(unsigned long long*)(AsH + off) = hq;
                *(unsigned long long*)(AsL + off) = lq;
            }
        }
        __syncthreads();

        // ---- compute: k-group g = l>>4 (consistent A/B pairing)
        const int g = l >> 4;
        bf16x8 ah[MT], al[MT];
        #pragma unroll
        for (int mt = 0; mt < MT; ++mt) {
            int ar = w * 16 * MT + mt * 16 + (l & 15);
            int off = ar * 64 + ((g ^ (ar & 3)) << 4);
            ah[mt] = *(const bf16x8*)(AsH + off);
            al[mt] = *(const bf16x8*)(AsL + off);
        }
        #pragma unroll
        for (int nt = 0; nt < 8; ++nt) {
            int bc = nt * 16 + (l & 15);
            int off = bc * 64 + ((g ^ (bc & 3)) << 4);
            bf16x8 bh = *(const bf16x8*)(WsH + off);
            bf16x8 bl = *(const bf16x8*)(WsL + off);
            #pragma unroll
            for (int mt = 0; mt < MT; ++mt) {
                acc[mt][nt] = __builtin_amdgcn_mfma_f32_16x16x32_bf16(ah[mt], bh, acc[mt][nt], 0, 0, 0);
                acc[mt][nt] = __builtin_amdgcn_mfma_f32_16x16x32_bf16(ah[mt], bl, acc[mt][nt], 0, 0, 0);
                acc[mt][nt] = __builtin_amdgcn_mfma_f32_16x16x32_bf16(al[mt], bh, acc[mt][nt], 0, 0, 0);
            }
        }
    }

    // epilogue: C/D layout col = lane&15, row = (lane>>4)*4 + j
    #pragma unroll
    for (int mt = 0; mt < MT; ++mt) {
        long r0 = rowbase + w * 16 * MT + mt * 16 + (l >> 4) * 4;
        #pragma unroll
        for (int nt = 0; nt < 8; ++nt) {
            int c = colbase + nt * 16 + (l & 15);
            #pragma unroll
            for (int j = 0; j < 4; ++j)
                out[(size_t)(r0 + j) * NC + c] = acc[mt][nt][j];
        }
    }
    if (DOSTATS) {
        #pragma unroll
        for (int nt = 0; nt < 8; ++nt) {
            float s = 0.f, qq = 0.f;
            #pragma unroll
            for (int mt = 0; mt < MT; ++mt)
                #pragma unroll
                for (int j = 0; j < 4; ++j) {
                    float v = acc[mt][nt][j];
                    s += v;
                    qq = fmaf(v, v, qq);
                }
            int ch = nt * 16 + (l & 15);
            atomicAdd(&chS[ch], s);
            atomicAdd(&chQ[ch], qq);
        }
        __syncthreads();
        if (tid < 128) {
            atomicAdd(&sums[colbase + tid], chS[tid]);
            atomicAdd(&sqs[colbase + tid], chQ[tid]);
        }
    }
}

__global__ void finalize_kernel(const float* __restrict__ sums, const float* __restrict__ sqs,
                                const float* __restrict__ g, const float* __restrict__ be,
                                float* __restrict__ scale, float* __restrict__ shift,
                                int C, float invR) {
    int c = threadIdx.x;
    if (c < C) {
        float mean = sums[c] * invR;
        float var = sqs[c] * invR - mean * mean;
        float a = g[c] * rsqrtf(var + 1e-5f);
        scale[c] = a;
        shift[c] = fmaf(-mean, a, be[c]);
    }
}

__global__ void bnapply_kernel(const float4* __restrict__ h4,
                               const float* __restrict__ scale, const float* __restrict__ shift,
                               float4* __restrict__ out4, int n4) {
    int i = blockIdx.x * 256 + threadIdx.x;
    if (i >= n4) return;
    float4 v = h4[i];
    int cb = (i & 31) << 2;
    float4 sc = *(const float4*)&scale[cb];
    float4 sh = *(const float4*)&shift[cb];
    v.x = fmaxf(fmaf(sc.x, v.x, sh.x), 0.f);
    v.y = fmaxf(fmaf(sc.y, v.y, sh.y), 0.f);
    v.z = fmaxf(fmaf(sc.z, v.z, sh.z), 0.f);
    v.w = fmaxf(fmaf(sc.w, v.w, sh.w), 0.f);
    out4[i] = v;
}

extern "C" void kernel_launch(void* const* d_in, const int* in_sizes, int n_in,
                              void* d_out, int out_size, void* d_ws, size_t ws_size,
                              hipStream_t stream) {
    const float* x   = (const float*)d_in[0];
    const int*   ei  = (const int*)d_in[1];
    const float* ew  = (const float*)d_in[2];
    const float* W0  = (const float*)d_in[3];
    const float* g0  = (const float*)d_in[5];
    const float* be0 = (const float*)d_in[6];
    const float* W1  = (const float*)d_in[7];
    const float* g1  = (const float*)d_in[9];
    const float* be1 = (const float*)d_in[10];
    float* out = (float*)d_out;

    const int N = in_sizes[0] / TF;   // 20000
    const int E = in_sizes[1] / 2;    // 320000
    const int ROWS = N * T_DIM;       // 80000

    const int* src = ei;
    const int* dst = ei + E;

    // workspace layout (~171 MB)
    float* h1  = (float*)d_ws;                          // ROWS*256 f32
    float* y2  = h1 + (size_t)ROWS * HID;               // ROWS*128 f32
    float* h2  = y2 + (size_t)ROWS * F_DIM;             // ROWS*128 f32; aliased:
    ushort* A1h = (ushort*)h2;                          //   ROWS*128 bf16 (agg1 out)
    ushort* A1l = A1h + (size_t)ROWS * F_DIM;           //   ROWS*128 bf16
    int* deg       = (int*)(h2 + (size_t)ROWS * F_DIM); // N
    int* row_start = deg + N;                           // N+1
    int* cursor    = row_start + N + 1;                 // N (+pad)
    int* esrc      = cursor + N + 3;                    // E (16B-aligned)
    float* ewr     = (float*)(esrc + E);                // E*4
    float* sums0   = ewr + (size_t)E * 4;               // 256
    float* sqs0    = sums0 + HID;
    float* sums1   = sqs0 + HID;                        // 128
    float* sqs1    = sums1 + F_DIM;
    float* scale0  = sqs1 + F_DIM;                      // 256
    float* shift0  = scale0 + HID;
    float* scale1  = shift0 + HID;                      // 128
    float* shift1  = scale1 + F_DIM;
    ushort* Wt0h   = (ushort*)(shift1 + F_DIM);         // 256*128
    ushort* Wt0l   = Wt0h + 256 * 128;
    ushort* Wt1h   = Wt0l + 256 * 128;                  // 128*256
    ushort* Wt1l   = Wt1h + 128 * 256;

    hipMemsetAsync(deg, 0, N * sizeof(int), stream);
    hipMemsetAsync(sums0, 0, (2 * HID + 2 * F_DIM) * sizeof(float), stream);

    const int eb = (E + 255) / 256;
    count_kernel<<<eb, 256, 0, stream>>>(dst, E, deg);
    scan_kernel<<<1, 1024, 0, stream>>>(deg, row_start, cursor, N);
    fill_kernel<<<eb, 256, 0, stream>>>(src, dst, (const float4*)ew, E, cursor,
                                        esrc, (float4*)ewr);
    wsplit_kernel<<<128, 256, 0, stream>>>(W0, 128, 256, Wt0h, Wt0l);
    wsplit_kernel<<<128, 256, 0, stream>>>(W1, 256, 128, Wt1h, Wt1l);

    // Layer 1: gather-first (bf16 split out), MFMA GEMM 128->256 with fused stats
    agg_kernel<true, false><<<N, 256, 0, stream>>>((const float4*)x, ewr, row_start,
                                                   esrc, nullptr, A1h, A1l,
                                                   nullptr, nullptr);
    gemm_mfma<128, 128, 256, false, true><<<dim3(2, ROWS / 128), 256, 0, stream>>>(
        A1h, A1l, nullptr, Wt0h, Wt0l, nullptr, nullptr, h1, sums0, sqs0);
    finalize_kernel<<<1, 256, 0, stream>>>(sums0, sqs0, g0, be0, scale0, shift0, HID,
                                           1.f / (float)ROWS);

    // Layer 2: BN+ReLU+split fused into A staging; MFMA GEMM 256->128;
    // gather after with fused stats
    gemm_mfma<64, 256, 128, true, false><<<dim3(1, ROWS / 64), 256, 0, stream>>>(
        nullptr, nullptr, h1, Wt1h, Wt1l, scale0, shift0, y2, nullptr, nullptr);
    agg_kernel<false, true><<<N, 256, 0, stream>>>((const float4*)y2, ewr, row_start,
                                                   esrc, (float4*)h2, nullptr, nullptr,
                                                   sums1, sqs1);
    finalize_kernel<<<1, 128, 0, stream>>>(sums1, sqs1, g1, be1, scale1, shift1, F_DIM,
                                           1.f / (float)ROWS);
    bnapply_kernel<<<(ROWS * F_DIM / 4 + 255) / 256, 256, 0, stream>>>(
        (const float4*)h2, scale1, shift1, (float4*)out, ROWS * F_DIM / 4);
}